// Round 1
// baseline (70.765 us; speedup 1.0000x reference)
//
#include <hip/hip_runtime.h>
#include <math.h>

// Problem constants (reference: N, M, D_IN = 2048, 2048, 16)
constexpr int N_ROWS = 2048;
constexpr int M_COLS = 2048;
constexpr int D = 16;

constexpr int BM = 256;  // columns per block (= blockDim.x), coalesced stores
constexpr int BN = 16;   // rows per block tile (grid.y = 128 -> 16 waves/CU)

typedef float f2 __attribute__((ext_vector_type(2)));

static __device__ __forceinline__ f2 mk2(float a, float b) {
  f2 r;
  r.x = a;
  r.y = b;
  return r;
}

// out[n,m] = var * exp(-0.5*sq) * ( S + (D-1-sq)*wsum )
// Refactored so X is consumed RAW (block-uniform loads -> s_load / L1 bcast):
//   w_d  = 1/ls_d^2,  a2_d = x2_d*w_d,  a2w_d = x2_d*w_d^2
//   dot  = sum_d x_d * a2_d          ( == dot(xl, x2l) )
//   dotw = sum_d x_d * a2w_d         ( == dot(xl, x2l*w) )
//   xs_n = sum_d x_d^2 w_d,  xw_n = sum_d x_d^2 w_d^2   (staged per block row)
//   X2s  = sum_d x2_d^2 w_d, X2w  = sum_d x2_d^2 w_d^2  (per thread column)
//   sq = xs + X2s - 2 dot ;  S = xw + X2w - 2 dotw
__global__ __launch_bounds__(256, 4) void dfk_kernel(
    const float* __restrict__ X, const float* __restrict__ X2,
    const float* __restrict__ uls, const float* __restrict__ uv,
    float* __restrict__ out) {
  __shared__ __align__(16) float sh_w[D + 1];  // w[16], var
  __shared__ float2 shS[BN];                   // per-row (xs, xw)

  const int tid = threadIdx.x;
  const int m = blockIdx.x * BM + tid;
  const int n0 = blockIdx.y * BN;

  // --- cooperative softplus: lanes 0..15 -> w=1/ls^2, lane 16 -> var ---
  if (tid <= D) {
    const float u = (tid < D) ? uls[tid] : uv[0];
    const float sp = fmaxf(u, 0.f) + log1pf(__expf(-fabsf(u)));  // stable
    if (tid < D) {
      const float il = 1.f / sp;
      sh_w[tid] = il * il;
    } else {
      sh_w[D] = sp;  // var
    }
  }
  __syncthreads();

  // --- broadcast params into registers ---
  float w[D];
  float wsum = 0.f;
#pragma unroll
  for (int q = 0; q < 4; ++q) {
    const float4 wq = ((const float4*)sh_w)[q];
    w[4 * q + 0] = wq.x;
    w[4 * q + 1] = wq.y;
    w[4 * q + 2] = wq.z;
    w[4 * q + 3] = wq.w;
    wsum += wq.x + wq.y + wq.z + wq.w;
  }
  const float var = sh_w[D];

  // --- this thread's X2 column: a2 = x2*w, a2w = x2*w^2 (+ its sums) ---
  f2 a2[8], a2w[8];
  float X2s = 0.f, X2w = 0.f;
  {
    const float4* x2r = (const float4*)(X2 + (size_t)m * D);
#pragma unroll
    for (int q = 0; q < 4; ++q) {
      const float4 v = x2r[q];
      const float a0 = v.x * w[4 * q + 0];
      const float a1 = v.y * w[4 * q + 1];
      const float b0 = v.z * w[4 * q + 2];
      const float b1 = v.w * w[4 * q + 3];
      X2s = fmaf(v.x, a0, X2s);
      X2s = fmaf(v.y, a1, X2s);
      X2s = fmaf(v.z, b0, X2s);
      X2s = fmaf(v.w, b1, X2s);
      X2w = fmaf(a0, a0, X2w);
      X2w = fmaf(a1, a1, X2w);
      X2w = fmaf(b0, b0, X2w);
      X2w = fmaf(b1, b1, X2w);
      a2[2 * q + 0] = mk2(a0, a1);
      a2[2 * q + 1] = mk2(b0, b1);
      a2w[2 * q + 0] = mk2(a0 * w[4 * q + 0], a1 * w[4 * q + 1]);
      a2w[2 * q + 1] = mk2(b0 * w[4 * q + 2], b1 * w[4 * q + 3]);
    }
  }

  // --- stage per-row (xs, xw) for this block's BN rows ---
  if (tid < BN) {
    const float4* xr = (const float4*)(X + (size_t)(n0 + tid) * D);
    float xs = 0.f, xw = 0.f;
#pragma unroll
    for (int q = 0; q < 4; ++q) {
      const float4 v = xr[q];
      const float t0 = v.x * v.x;
      const float t1 = v.y * v.y;
      const float t2 = v.z * v.z;
      const float t3 = v.w * v.w;
      xs = fmaf(t0, w[4 * q + 0], xs);
      xs = fmaf(t1, w[4 * q + 1], xs);
      xs = fmaf(t2, w[4 * q + 2], xs);
      xs = fmaf(t3, w[4 * q + 3], xs);
      xw = fmaf(t0, w[4 * q + 0] * w[4 * q + 0], xw);
      xw = fmaf(t1, w[4 * q + 1] * w[4 * q + 1], xw);
      xw = fmaf(t2, w[4 * q + 2] * w[4 * q + 2], xw);
      xw = fmaf(t3, w[4 * q + 3] * w[4 * q + 3], xw);
    }
    shS[tid] = make_float2(xs, xw);
  }
  __syncthreads();

  const float cS = ((float)D - 1.f) * wsum;

#pragma unroll 4
  for (int i = 0; i < BN; ++i) {
    // block-uniform address: candidate for s_load / L1 broadcast
    const float4* xr = (const float4*)(X + (size_t)(n0 + i) * D);
    const float4 r0 = xr[0];
    const float4 r1 = xr[1];
    const float4 r2 = xr[2];
    const float4 r3 = xr[3];

    f2 acc = mk2(0.f, 0.f);
    f2 accw = mk2(0.f, 0.f);
    f2 s;
    s = mk2(r0.x, r0.y);
    acc = __builtin_elementwise_fma(s, a2[0], acc);
    accw = __builtin_elementwise_fma(s, a2w[0], accw);
    s = mk2(r0.z, r0.w);
    acc = __builtin_elementwise_fma(s, a2[1], acc);
    accw = __builtin_elementwise_fma(s, a2w[1], accw);
    s = mk2(r1.x, r1.y);
    acc = __builtin_elementwise_fma(s, a2[2], acc);
    accw = __builtin_elementwise_fma(s, a2w[2], accw);
    s = mk2(r1.z, r1.w);
    acc = __builtin_elementwise_fma(s, a2[3], acc);
    accw = __builtin_elementwise_fma(s, a2w[3], accw);
    s = mk2(r2.x, r2.y);
    acc = __builtin_elementwise_fma(s, a2[4], acc);
    accw = __builtin_elementwise_fma(s, a2w[4], accw);
    s = mk2(r2.z, r2.w);
    acc = __builtin_elementwise_fma(s, a2[5], acc);
    accw = __builtin_elementwise_fma(s, a2w[5], accw);
    s = mk2(r3.x, r3.y);
    acc = __builtin_elementwise_fma(s, a2[6], acc);
    accw = __builtin_elementwise_fma(s, a2w[6], accw);
    s = mk2(r3.z, r3.w);
    acc = __builtin_elementwise_fma(s, a2[7], acc);
    accw = __builtin_elementwise_fma(s, a2w[7], accw);

    const float dot = acc.x + acc.y;
    const float dotw = accw.x + accw.y;
    const float2 xsxw = shS[i];  // ds_read_b64, broadcast
    const float sq = fmaf(-2.f, dot, xsxw.x + X2s);
    const float S = fmaf(-2.f, dotw, xsxw.y + X2w);
    const float k2 = __expf(-0.5f * sq);
    const float res = var * k2 * fmaf(-wsum, sq, cS + S);
    out[(size_t)(n0 + i) * M_COLS + m] = res;
  }
}

extern "C" void kernel_launch(void* const* d_in, const int* in_sizes, int n_in,
                              void* d_out, int out_size, void* d_ws, size_t ws_size,
                              hipStream_t stream) {
  const float* X = (const float*)d_in[0];    // (2048, 16)
  const float* X2 = (const float*)d_in[1];   // (2048, 16)
  const float* uls = (const float*)d_in[2];  // (16,)
  const float* uv = (const float*)d_in[3];   // (1,)
  float* out = (float*)d_out;                // (2048, 2048) fp32

  dim3 grid(M_COLS / BM, N_ROWS / BN);  // (8, 128) = 1024 blocks, 16 waves/CU
  dfk_kernel<<<grid, dim3(BM), 0, stream>>>(X, X2, uls, uv, out);
}